// Round 1
// baseline (263.538 us; speedup 1.0000x reference)
//
#include <hip/hip_runtime.h>
#include <math.h>

#define NEGV -1e9f
constexpr int B_ = 16, N_ = 1024, M_ = 128, D_ = 768;
constexpr int ROWS = 32, KT = 32;

// ws layout (float offsets):
//   [0,      2048)  q_logit[B][M]
//   [2048,  18432)  rowmax [B][N]   (raw row max of S, pre-mask)
//   [18432, 34816)  q2c weights [B][N]
//   [34816, 47104)  Bctx [B][D]

__global__ __launch_bounds__(256) void k_qlogit(const float* __restrict__ Q,
                                                const float* __restrict__ w2,
                                                float* __restrict__ qlog) {
    int idx  = blockIdx.x * 4 + (threadIdx.x >> 6);   // one wave per dot
    int lane = threadIdx.x & 63;
    const float* q = Q + (size_t)idx * D_;
    float s = 0.f;
    for (int k = lane; k < D_; k += 64) s += q[k] * w2[k];
#pragma unroll
    for (int off = 32; off; off >>= 1) s += __shfl_xor(s, off);
    if (lane == 0) qlog[idx] = s;
}

__global__ __launch_bounds__(256) void k_main(const float* __restrict__ C,
                                              const float* __restrict__ Q,
                                              const int* __restrict__ c_mask,
                                              const int* __restrict__ q_mask,
                                              const float* __restrict__ w1,
                                              const float* __restrict__ w3,
                                              const float* __restrict__ qlog,
                                              float* __restrict__ rowmax,
                                              float* __restrict__ out) {
    const int b  = blockIdx.x >> 5;          // 32 row-blocks per batch
    const int r0 = (blockIdx.x & 31) * ROWS;
    const int t  = threadIdx.x;
    const float* Cb = C + ((size_t)b * N_ + r0) * D_;
    const float* Qb = Q + (size_t)b * M_ * D_;

    __shared__ float sW1[D_];
    __shared__ float sW3[D_];
    __shared__ float sQk[KT][M_];        // Q^T chunk: [k][j]
    __shared__ float sCk[KT][ROWS + 4];  // (C*w3)^T chunk: [k][r], padded
    __shared__ float sClog[ROWS];
    __shared__ float sQlog[M_];
    __shared__ int   sQmask[M_];
    __shared__ float sP[ROWS][M_ + 4];   // C2Q, padded (132 floats: 16B aligned rows)
    __shared__ float sQ3[M_][64];        // phase-3 Q chunk [j][c]

    for (int k = t; k < D_; k += 256) { sW1[k] = w1[k]; sW3[k] = w3[k]; }
    if (t < M_) { sQlog[t] = qlog[b * M_ + t]; sQmask[t] = q_mask[b * M_ + t]; }

    const int trow = t >> 5, tcol = t & 31;      // compute map: 4 rows x 4 cols
    const int lrow = t >> 3, lq = t & 7;         // C loader: row, quad
    const int lj   = t >> 1, lq0 = (t & 1) * 4;  // Q loader: row j, first quad

    float acc[4][4] = {};
    float clogp = 0.f;

    // ---- Phase 1: S = (C*w3) @ Q^T over K=768 in KT=32 chunks ----
    for (int kb = 0; kb < D_; kb += KT) {
        __syncthreads();
        {
            float4 cv = *(const float4*)(Cb + (size_t)lrow * D_ + kb + lq * 4);
            int k0 = lq * 4;
            clogp += cv.x * sW1[kb + k0] + cv.y * sW1[kb + k0 + 1] +
                     cv.z * sW1[kb + k0 + 2] + cv.w * sW1[kb + k0 + 3];
            sCk[k0 + 0][lrow] = cv.x * sW3[kb + k0 + 0];
            sCk[k0 + 1][lrow] = cv.y * sW3[kb + k0 + 1];
            sCk[k0 + 2][lrow] = cv.z * sW3[kb + k0 + 2];
            sCk[k0 + 3][lrow] = cv.w * sW3[kb + k0 + 3];
        }
#pragma unroll
        for (int u = 0; u < 4; ++u) {
            int q4 = lq0 + u;
            float4 qv = *(const float4*)(Qb + (size_t)lj * D_ + kb + q4 * 4);
            sQk[q4 * 4 + 0][lj] = qv.x;
            sQk[q4 * 4 + 1][lj] = qv.y;
            sQk[q4 * 4 + 2][lj] = qv.z;
            sQk[q4 * 4 + 3][lj] = qv.w;
        }
        __syncthreads();
#pragma unroll
        for (int k = 0; k < KT; ++k) {
            float4 a = *(const float4*)&sCk[k][trow * 4];
            float4 q = *(const float4*)&sQk[k][tcol * 4];
            acc[0][0] += a.x * q.x; acc[0][1] += a.x * q.y; acc[0][2] += a.x * q.z; acc[0][3] += a.x * q.w;
            acc[1][0] += a.y * q.x; acc[1][1] += a.y * q.y; acc[1][2] += a.y * q.z; acc[1][3] += a.y * q.w;
            acc[2][0] += a.z * q.x; acc[2][1] += a.z * q.y; acc[2][2] += a.z * q.z; acc[2][3] += a.z * q.w;
            acc[3][0] += a.w * q.x; acc[3][1] += a.w * q.y; acc[3][2] += a.w * q.z; acc[3][3] += a.w * q.w;
        }
    }

    // finalize c_logit (8 loader-threads per row, adjacent lanes)
    clogp += __shfl_xor(clogp, 1);
    clogp += __shfl_xor(clogp, 2);
    clogp += __shfl_xor(clogp, 4);
    if ((t & 7) == 0) sClog[lrow] = clogp;
    __syncthreads();

    // ---- Phase 2: add logits, raw rowmax, masked softmax -> sP ----
    float qlg[4]; int qm[4];
#pragma unroll
    for (int cc = 0; cc < 4; ++cc) {
        qlg[cc] = sQlog[tcol * 4 + cc];
        qm[cc]  = sQmask[tcol * 4 + cc];
    }
#pragma unroll
    for (int rr = 0; rr < 4; ++rr) {
        int r = trow * 4 + rr;
        float clg = sClog[r];
        int cm = c_mask[b * N_ + r0 + r];
        float v0 = acc[rr][0] + clg + qlg[0];
        float v1 = acc[rr][1] + clg + qlg[1];
        float v2 = acc[rr][2] + clg + qlg[2];
        float v3 = acc[rr][3] + clg + qlg[3];
        float mraw = fmaxf(fmaxf(v0, v1), fmaxf(v2, v3));
#pragma unroll
        for (int off = 16; off; off >>= 1) mraw = fmaxf(mraw, __shfl_xor(mraw, off));
        if (tcol == 0) rowmax[b * N_ + r0 + r] = mraw;

        float m0 = (cm != 0 || qm[0] != 0) ? NEGV : v0;
        float m1 = (cm != 0 || qm[1] != 0) ? NEGV : v1;
        float m2 = (cm != 0 || qm[2] != 0) ? NEGV : v2;
        float m3 = (cm != 0 || qm[3] != 0) ? NEGV : v3;
        float mm = fmaxf(fmaxf(m0, m1), fmaxf(m2, m3));
#pragma unroll
        for (int off = 16; off; off >>= 1) mm = fmaxf(mm, __shfl_xor(mm, off));
        float p0 = __expf(m0 - mm), p1 = __expf(m1 - mm);
        float p2 = __expf(m2 - mm), p3 = __expf(m3 - mm);
        float ps = p0 + p1 + p2 + p3;
#pragma unroll
        for (int off = 16; off; off >>= 1) ps += __shfl_xor(ps, off);
        float inv = 1.f / ps;
        sP[r][tcol * 4 + 0] = p0 * inv;
        sP[r][tcol * 4 + 1] = p1 * inv;
        sP[r][tcol * 4 + 2] = p2 * inv;
        sP[r][tcol * 4 + 3] = p3 * inv;
    }

    // ---- Phase 3: A = P @ Q, store to out[:, 768:1536) ----
    const int trow3 = t >> 4, tcol3 = t & 15;  // 2 rows x 4 cols per thread
    for (int db = 0; db < D_; db += 64) {
        __syncthreads();
#pragma unroll
        for (int u = 0; u < 8; ++u) {
            int qq = (t & 1) * 8 + u;
            *(float4*)&sQ3[lj][qq * 4] = *(const float4*)(Qb + (size_t)lj * D_ + db + qq * 4);
        }
        __syncthreads();
        float a0[4] = {0.f, 0.f, 0.f, 0.f}, a1[4] = {0.f, 0.f, 0.f, 0.f};
#pragma unroll 8
        for (int j = 0; j < M_; j += 4) {
            float4 p0 = *(const float4*)&sP[trow3 * 2 + 0][j];
            float4 p1 = *(const float4*)&sP[trow3 * 2 + 1][j];
            float4 q0 = *(const float4*)&sQ3[j + 0][tcol3 * 4];
            float4 q1 = *(const float4*)&sQ3[j + 1][tcol3 * 4];
            float4 q2 = *(const float4*)&sQ3[j + 2][tcol3 * 4];
            float4 q3 = *(const float4*)&sQ3[j + 3][tcol3 * 4];
            a0[0] += p0.x * q0.x + p0.y * q1.x + p0.z * q2.x + p0.w * q3.x;
            a0[1] += p0.x * q0.y + p0.y * q1.y + p0.z * q2.y + p0.w * q3.y;
            a0[2] += p0.x * q0.z + p0.y * q1.z + p0.z * q2.z + p0.w * q3.z;
            a0[3] += p0.x * q0.w + p0.y * q1.w + p0.z * q2.w + p0.w * q3.w;
            a1[0] += p1.x * q0.x + p1.y * q1.x + p1.z * q2.x + p1.w * q3.x;
            a1[1] += p1.x * q0.y + p1.y * q1.y + p1.z * q2.y + p1.w * q3.y;
            a1[2] += p1.x * q0.z + p1.y * q1.z + p1.z * q2.z + p1.w * q3.z;
            a1[3] += p1.x * q0.w + p1.y * q1.w + p1.z * q2.w + p1.w * q3.w;
        }
        size_t ob = ((size_t)b * N_ + r0 + trow3 * 2) * 3072 + 768 + db + tcol3 * 4;
        *(float4*)(out + ob)        = make_float4(a0[0], a0[1], a0[2], a0[3]);
        *(float4*)(out + ob + 3072) = make_float4(a1[0], a1[1], a1[2], a1[3]);
    }
}

__global__ __launch_bounds__(256) void k_q2c(const float* __restrict__ rowmax,
                                             const int* __restrict__ c_mask,
                                             float* __restrict__ wq2c) {
    int b = blockIdx.x, t = threadIdx.x;
    __shared__ float red[8];
    float l[4];
#pragma unroll
    for (int u = 0; u < 4; ++u) {
        int i = t + u * 256;
        l[u] = (c_mask[b * N_ + i] != 0) ? NEGV : rowmax[b * N_ + i];
    }
    float mx = fmaxf(fmaxf(l[0], l[1]), fmaxf(l[2], l[3]));
#pragma unroll
    for (int off = 32; off; off >>= 1) mx = fmaxf(mx, __shfl_xor(mx, off));
    if ((t & 63) == 0) red[t >> 6] = mx;
    __syncthreads();
    mx = fmaxf(fmaxf(red[0], red[1]), fmaxf(red[2], red[3]));
    float e[4], s = 0.f;
#pragma unroll
    for (int u = 0; u < 4; ++u) { e[u] = __expf(l[u] - mx); s += e[u]; }
#pragma unroll
    for (int off = 32; off; off >>= 1) s += __shfl_xor(s, off);
    if ((t & 63) == 0) red[4 + (t >> 6)] = s;
    __syncthreads();
    s = red[4] + red[5] + red[6] + red[7];
    float inv = 1.f / s;
#pragma unroll
    for (int u = 0; u < 4; ++u) wq2c[b * N_ + t + u * 256] = e[u] * inv;
}

__global__ __launch_bounds__(256) void k_bctx(const float* __restrict__ C,
                                              const float* __restrict__ wq2c,
                                              float* __restrict__ Bctx) {
    int b  = blockIdx.x / 12;
    int c0 = (blockIdx.x % 12) * 64;
    int t  = threadIdx.x;
    int col = t & 63, ig = t >> 6;
    __shared__ float part[4][64];
    const float* wb = wq2c + b * N_;
    const float* Cb = C + (size_t)b * N_ * D_;
    float s = 0.f;
    for (int i = ig * 256; i < ig * 256 + 256; ++i)
        s += wb[i] * Cb[(size_t)i * D_ + c0 + col];
    part[ig][col] = s;
    __syncthreads();
    if (t < 64) Bctx[b * D_ + c0 + t] = part[0][t] + part[1][t] + part[2][t] + part[3][t];
}

__global__ __launch_bounds__(192) void k_epilogue(const float* __restrict__ C,
                                                  const float* __restrict__ Bctx,
                                                  float* __restrict__ out) {
    int row = blockIdx.x;
    int b = row >> 10;
    int t = threadIdx.x;  // 0..191, covers 768 floats as float4
    size_t obase = (size_t)row * 3072;
    float4 c = *(const float4*)(C + (size_t)row * D_ + t * 4);
    float4 a = *(const float4*)(out + obase + 768 + t * 4);
    float4 g = *(const float4*)(Bctx + (size_t)b * D_ + t * 4);
    *(float4*)(out + obase + t * 4) = c;
    *(float4*)(out + obase + 1536 + t * 4) = make_float4(c.x * a.x, c.y * a.y, c.z * a.z, c.w * a.w);
    *(float4*)(out + obase + 2304 + t * 4) = make_float4(c.x * g.x, c.y * g.y, c.z * g.z, c.w * g.w);
}

extern "C" void kernel_launch(void* const* d_in, const int* in_sizes, int n_in,
                              void* d_out, int out_size, void* d_ws, size_t ws_size,
                              hipStream_t stream) {
    const float* C      = (const float*)d_in[0];
    const float* Q      = (const float*)d_in[1];
    const int*   c_mask = (const int*)d_in[2];
    const int*   q_mask = (const int*)d_in[3];
    const float* w1     = (const float*)d_in[4];
    const float* w2     = (const float*)d_in[5];
    const float* w3     = (const float*)d_in[6];
    float* out = (float*)d_out;
    float* ws  = (float*)d_ws;

    float* qlog   = ws;
    float* rowmax = ws + 2048;
    float* wq2c   = ws + 18432;
    float* Bctx   = ws + 34816;

    k_qlogit<<<512, 256, 0, stream>>>(Q, w2, qlog);
    k_main<<<512, 256, 0, stream>>>(C, Q, c_mask, q_mask, w1, w3, qlog, rowmax, out);
    k_q2c<<<16, 256, 0, stream>>>(rowmax, c_mask, wq2c);
    k_bctx<<<192, 256, 0, stream>>>(C, wq2c, Bctx);
    k_epilogue<<<16384, 192, 0, stream>>>(C, Bctx, out);
}

// Round 2
// 131.857 us; speedup vs baseline: 1.9987x; 1.9987x over previous
//
#include <hip/hip_runtime.h>
#include <math.h>

#define NEGV -1e9f
typedef float f32x4 __attribute__((ext_vector_type(4)));
typedef short bf16x8 __attribute__((ext_vector_type(8)));
typedef unsigned int u32x4 __attribute__((ext_vector_type(4)));

constexpr int B_ = 16, N_ = 1024, M_ = 128, D_ = 768;

// ws layout (float offsets):
//   [0,      2048)  q_logit[B][M]
//   [2048,  18432)  rowmax [B][N]   (raw row max of S, pre-c_mask)
//   [18432, 34816)  q2c weights [B][N]
//   [34816, 47104)  Bctx [B][D]

__device__ __forceinline__ unsigned short bf_rne(float x) {
    unsigned u = __float_as_uint(x);
    return (unsigned short)((u + 0x7fffu + ((u >> 16) & 1u)) >> 16);
}
__device__ __forceinline__ void splitf(float x, unsigned short& h, unsigned short& l) {
    unsigned short hb = bf_rne(x);
    float hf = __uint_as_float((unsigned)hb << 16);
    h = hb;
    l = bf_rne(x - hf);
}

__global__ __launch_bounds__(256) void k_qlogit(const float* __restrict__ Q,
                                                const float* __restrict__ w2,
                                                float* __restrict__ qlog) {
    int idx  = blockIdx.x * 4 + (threadIdx.x >> 6);
    int lane = threadIdx.x & 63;
    const float* q = Q + (size_t)idx * D_;
    float s = 0.f;
    for (int k = lane; k < D_; k += 64) s += q[k] * w2[k];
#pragma unroll
    for (int off = 32; off; off >>= 1) s += __shfl_xor(s, off);
    if (lane == 0) qlog[idx] = s;
}

// 512 blocks: b = blk>>5, 32 rows each. 4 waves: (row-group rg = w>>1) x (half jh = w&1).
// Phase 1: S = (C*w3) @ Q^T via split-bf16 MFMA. Phase 2: softmax (cross-wave over j halves).
// Phase 3: A = P @ Q via MFMA, fused epilogue writes out[:,0:768)=C, [768:1536)=A, [1536:2304)=C*A.
__global__ __launch_bounds__(256, 2) void k_main(const float* __restrict__ C,
                                                 const float* __restrict__ Q,
                                                 const int* __restrict__ c_mask,
                                                 const int* __restrict__ q_mask,
                                                 const float* __restrict__ w1,
                                                 const float* __restrict__ w3,
                                                 const float* __restrict__ qlog,
                                                 float* __restrict__ rowmax,
                                                 float* __restrict__ out) {
    const int b  = blockIdx.x >> 5;
    const int r0 = (blockIdx.x & 31) * 32;
    const int t  = threadIdx.x;
    const int wv = t >> 6;
    const int rg = wv >> 1, jh = wv & 1;     // phase3: rg = row-group, jh = d-half
    const int q4 = (t & 63) >> 4, c15 = t & 15;

    const float* Cb = C + ((size_t)(b * N_ + r0)) * D_;
    const float* Qb = Q + (size_t)b * M_ * D_;

    __shared__ __align__(16) char uni[49152];
    __shared__ float sW1[D_], sW3[D_];
    __shared__ float sQlog[M_];
    __shared__ int   sQmask[M_];
    __shared__ float sClog[32];
    __shared__ float sRedR[32 * 2], sRedM[32 * 2], sRedS[32 * 2];

    char* sCwH = uni;                 // [32 r][8 g][16B] swizzled g^(r&7)
    char* sCwL = uni + 4096;
    char* sQH  = uni + 8192;          // [128 j][8 g][16B] swizzled g^(j&7)
    char* sQL  = uni + 24576;
    char* sPt  = uni;                 // phase2/3: [32 r][32 gu][16B] packed u32=(hi<<16|lo), gu^(r&7)
    char* sQtP = uni + 16384;         // phase3:   [64 d][32 gu][16B] packed u32, gu^(d&7)

    for (int k = t; k < D_; k += 256) { sW1[k] = w1[k]; sW3[k] = w3[k]; }
    if (t < M_) { sQlog[t] = qlog[b * M_ + t]; sQmask[t] = q_mask[b * M_ + t]; }

    f32x4 acc[4] = {};
    float clog = 0.f;

    const int cr = t >> 3, ckq = t & 7;         // C staging: row, k-group-of-8
    const int qj = t >> 1, qk0 = (t & 1) * 32;  // Q staging: j-row, k-half

    // ---- Phase 1 ----
    for (int kb = 0; kb < D_; kb += 64) {
        __syncthreads();
        {   // stage C*w3 -> hi/lo bf16, accumulate c_logit
            const float* p = Cb + (size_t)cr * D_ + kb + ckq * 8;
            float4 a  = *(const float4*)p;
            float4 bb = *(const float4*)(p + 4);
            float cc[8] = {a.x, a.y, a.z, a.w, bb.x, bb.y, bb.z, bb.w};
            bf16x8 hv, lv;
            int kk = kb + ckq * 8;
#pragma unroll
            for (int e = 0; e < 8; ++e) {
                clog += cc[e] * sW1[kk + e];
                unsigned short h, l;
                splitf(cc[e] * sW3[kk + e], h, l);
                hv[e] = (short)h; lv[e] = (short)l;
            }
            int pg = (ckq ^ (cr & 7)) * 16;
            *(bf16x8*)(sCwH + cr * 128 + pg) = hv;
            *(bf16x8*)(sCwL + cr * 128 + pg) = lv;
        }
        {   // stage Q -> hi/lo bf16
            const float* p = Qb + (size_t)qj * D_ + kb + qk0;
#pragma unroll
            for (int u = 0; u < 4; ++u) {
                float4 a  = *(const float4*)(p + u * 8);
                float4 bb = *(const float4*)(p + u * 8 + 4);
                float qq[8] = {a.x, a.y, a.z, a.w, bb.x, bb.y, bb.z, bb.w};
                bf16x8 hv, lv;
#pragma unroll
                for (int e = 0; e < 8; ++e) {
                    unsigned short h, l;
                    splitf(qq[e], h, l);
                    hv[e] = (short)h; lv[e] = (short)l;
                }
                int g  = (t & 1) * 4 + u;
                int pg = (g ^ (qj & 7)) * 16;
                *(bf16x8*)(sQH + qj * 128 + pg) = hv;
                *(bf16x8*)(sQL + qj * 128 + pg) = lv;
            }
        }
        __syncthreads();
        const int arow = rg * 16 + c15;
#pragma unroll
        for (int ks = 0; ks < 2; ++ks) {
            int g  = ks * 4 + q4;
            int pg = (g ^ (c15 & 7)) * 16;
            bf16x8 ah = *(const bf16x8*)(sCwH + arow * 128 + pg);
            bf16x8 al = *(const bf16x8*)(sCwL + arow * 128 + pg);
#pragma unroll
            for (int jt = 0; jt < 4; ++jt) {
                int jr = jh * 64 + jt * 16 + c15;
                bf16x8 bh = *(const bf16x8*)(sQH + jr * 128 + pg);
                bf16x8 bl = *(const bf16x8*)(sQL + jr * 128 + pg);
                acc[jt] = __builtin_amdgcn_mfma_f32_16x16x32_bf16(ah, bh, acc[jt], 0, 0, 0);
                acc[jt] = __builtin_amdgcn_mfma_f32_16x16x32_bf16(ah, bl, acc[jt], 0, 0, 0);
                acc[jt] = __builtin_amdgcn_mfma_f32_16x16x32_bf16(al, bh, acc[jt], 0, 0, 0);
            }
        }
    }

    // ---- Phase 2: logits + softmax over j (cross-wave combine of the two j-halves) ----
    clog += __shfl_xor(clog, 1); clog += __shfl_xor(clog, 2); clog += __shfl_xor(clog, 4);
    if ((t & 7) == 0) sClog[cr] = clog;
    __syncthreads();

    float qlg[4]; int qmv[4];
#pragma unroll
    for (int jt = 0; jt < 4; ++jt) {
        int j = jh * 64 + jt * 16 + c15;
        qlg[jt] = sQlog[j]; qmv[jt] = sQmask[j];
    }
    int cmv[4]; float clgr[4];
#pragma unroll
    for (int rr = 0; rr < 4; ++rr) {
        int row = rg * 16 + q4 * 4 + rr;
        cmv[rr]  = c_mask[b * N_ + r0 + row];
        clgr[rr] = sClog[row];
    }
    float mv[4][4], rmx[4], mmx[4];
#pragma unroll
    for (int rr = 0; rr < 4; ++rr) { rmx[rr] = -INFINITY; mmx[rr] = -INFINITY; }
#pragma unroll
    for (int jt = 0; jt < 4; ++jt)
#pragma unroll
        for (int rr = 0; rr < 4; ++rr) {
            float val = acc[jt][rr] + clgr[rr] + qlg[jt];
            float m   = (cmv[rr] | qmv[jt]) ? NEGV : val;
            mv[jt][rr] = m;
            rmx[rr] = fmaxf(rmx[rr], val);
            mmx[rr] = fmaxf(mmx[rr], m);
        }
#pragma unroll
    for (int rr = 0; rr < 4; ++rr)
#pragma unroll
        for (int off = 8; off; off >>= 1) {
            rmx[rr] = fmaxf(rmx[rr], __shfl_xor(rmx[rr], off));
            mmx[rr] = fmaxf(mmx[rr], __shfl_xor(mmx[rr], off));
        }
    if (c15 == 0) {
#pragma unroll
        for (int rr = 0; rr < 4; ++rr) {
            int row = rg * 16 + q4 * 4 + rr;
            sRedR[row * 2 + jh] = rmx[rr];
            sRedM[row * 2 + jh] = mmx[rr];
        }
    }
    __syncthreads();
    float Mm[4], sum[4];
#pragma unroll
    for (int rr = 0; rr < 4; ++rr) {
        int row = rg * 16 + q4 * 4 + rr;
        float Mraw = fmaxf(sRedR[row * 2], sRedR[row * 2 + 1]);
        Mm[rr] = fmaxf(sRedM[row * 2], sRedM[row * 2 + 1]);
        if (jh == 0 && c15 == 0) rowmax[b * N_ + r0 + row] = Mraw;
        sum[rr] = 0.f;
    }
    float p[4][4];
#pragma unroll
    for (int jt = 0; jt < 4; ++jt)
#pragma unroll
        for (int rr = 0; rr < 4; ++rr) {
            float e = __expf(mv[jt][rr] - Mm[rr]);
            p[jt][rr] = e; sum[rr] += e;
        }
#pragma unroll
    for (int rr = 0; rr < 4; ++rr) {
#pragma unroll
        for (int off = 8; off; off >>= 1) sum[rr] += __shfl_xor(sum[rr], off);
        if (c15 == 0) sRedS[(rg * 16 + q4 * 4 + rr) * 2 + jh] = sum[rr];
    }
    __syncthreads();
#pragma unroll
    for (int rr = 0; rr < 4; ++rr) {
        int row = rg * 16 + q4 * 4 + rr;
        float inv = 1.f / (sRedS[row * 2] + sRedS[row * 2 + 1]);
#pragma unroll
        for (int jt = 0; jt < 4; ++jt) {
            float P = p[jt][rr] * inv;
            unsigned short h, l; splitf(P, h, l);
            unsigned pk = ((unsigned)h << 16) | (unsigned)l;
            int j  = jh * 64 + jt * 16 + c15;
            int gu = j >> 2;
            *(unsigned*)(sPt + row * 512 + ((gu ^ (row & 7)) * 16) + (j & 3) * 4) = pk;
        }
    }

    // ---- Phase 3: A = P @ Q + fused epilogue ----
    const int pj = t >> 1, pdh = (t & 1) * 32;  // staging: j-row, d-half
    for (int d0 = 0; d0 < D_; d0 += 64) {
        __syncthreads();
        {   // stage Q^T packed (hi<<16|lo) with transpose
            const float* p = Qb + (size_t)pj * D_ + d0 + pdh;
            int gu = pj >> 2, joff = (pj & 3) * 4;
#pragma unroll
            for (int u = 0; u < 8; ++u) {
                float4 a = *(const float4*)(p + u * 4);
                float qq[4] = {a.x, a.y, a.z, a.w};
#pragma unroll
                for (int e = 0; e < 4; ++e) {
                    unsigned short h, l; splitf(qq[e], h, l);
                    int d = pdh + u * 4 + e;
                    *(unsigned*)(sQtP + d * 512 + ((gu ^ (d & 7)) * 16) + joff) =
                        ((unsigned)h << 16) | (unsigned)l;
                }
            }
        }
        __syncthreads();
        f32x4 acc2[2] = {};
        const int prow = rg * 16 + c15;
#pragma unroll
        for (int ks2 = 0; ks2 < 4; ++ks2) {
            int gu0 = ks2 * 8 + q4 * 2;
            u32x4 pa = *(const u32x4*)(sPt + prow * 512 + ((gu0 ^ (c15 & 7)) * 16));
            u32x4 pb = *(const u32x4*)(sPt + prow * 512 + (((gu0 + 1) ^ (c15 & 7)) * 16));
            bf16x8 phi, plo;
#pragma unroll
            for (int e = 0; e < 4; ++e) {
                phi[e]     = (short)(pa[e] >> 16); plo[e]     = (short)(pa[e] & 0xffffu);
                phi[e + 4] = (short)(pb[e] >> 16); plo[e + 4] = (short)(pb[e] & 0xffffu);
            }
#pragma unroll
            for (int dt = 0; dt < 2; ++dt) {
                int dr = jh * 32 + dt * 16 + c15;
                u32x4 qa = *(const u32x4*)(sQtP + dr * 512 + ((gu0 ^ (dr & 7)) * 16));
                u32x4 qb = *(const u32x4*)(sQtP + dr * 512 + (((gu0 + 1) ^ (dr & 7)) * 16));
                bf16x8 bh, bl;
#pragma unroll
                for (int e = 0; e < 4; ++e) {
                    bh[e]     = (short)(qa[e] >> 16); bl[e]     = (short)(qa[e] & 0xffffu);
                    bh[e + 4] = (short)(qb[e] >> 16); bl[e + 4] = (short)(qb[e] & 0xffffu);
                }
                acc2[dt] = __builtin_amdgcn_mfma_f32_16x16x32_bf16(phi, bh, acc2[dt], 0, 0, 0);
                acc2[dt] = __builtin_amdgcn_mfma_f32_16x16x32_bf16(phi, bl, acc2[dt], 0, 0, 0);
                acc2[dt] = __builtin_amdgcn_mfma_f32_16x16x32_bf16(plo, bh, acc2[dt], 0, 0, 0);
            }
        }
        // fused epilogue: C, A, C*A
#pragma unroll
        for (int dt = 0; dt < 2; ++dt)
#pragma unroll
            for (int rr = 0; rr < 4; ++rr) {
                int row  = rg * 16 + q4 * 4 + rr;
                int dcol = d0 + jh * 32 + dt * 16 + c15;
                float a = acc2[dt][rr];
                float c = Cb[(size_t)row * D_ + dcol];
                size_t ob = (size_t)(b * N_ + r0 + row) * 3072;
                out[ob + dcol] = c;
                out[ob + 768 + dcol] = a;
                out[ob + 1536 + dcol] = c * a;
            }
    }
}

__global__ __launch_bounds__(256) void k_q2c(const float* __restrict__ rowmax,
                                             const int* __restrict__ c_mask,
                                             float* __restrict__ wq2c) {
    int b = blockIdx.x, t = threadIdx.x;
    __shared__ float red[8];
    float l[4];
#pragma unroll
    for (int u = 0; u < 4; ++u) {
        int i = t + u * 256;
        l[u] = (c_mask[b * N_ + i] != 0) ? NEGV : rowmax[b * N_ + i];
    }
    float mx = fmaxf(fmaxf(l[0], l[1]), fmaxf(l[2], l[3]));
#pragma unroll
    for (int off = 32; off; off >>= 1) mx = fmaxf(mx, __shfl_xor(mx, off));
    if ((t & 63) == 0) red[t >> 6] = mx;
    __syncthreads();
    mx = fmaxf(fmaxf(red[0], red[1]), fmaxf(red[2], red[3]));
    float e[4], s = 0.f;
#pragma unroll
    for (int u = 0; u < 4; ++u) { e[u] = __expf(l[u] - mx); s += e[u]; }
#pragma unroll
    for (int off = 32; off; off >>= 1) s += __shfl_xor(s, off);
    if ((t & 63) == 0) red[4 + (t >> 6)] = s;
    __syncthreads();
    s = red[4] + red[5] + red[6] + red[7];
    float inv = 1.f / s;
#pragma unroll
    for (int u = 0; u < 4; ++u) wq2c[b * N_ + t + u * 256] = e[u] * inv;
}

__global__ __launch_bounds__(256) void k_bctx(const float* __restrict__ C,
                                              const float* __restrict__ wq2c,
                                              float* __restrict__ Bctx) {
    int b  = blockIdx.x / 12;
    int c0 = (blockIdx.x % 12) * 64;
    int t  = threadIdx.x;
    int col = t & 63, ig = t >> 6;
    __shared__ float part[4][64];
    const float* wb = wq2c + b * N_;
    const float* Cb = C + (size_t)b * N_ * D_;
    float s = 0.f;
    for (int i = ig * 256; i < ig * 256 + 256; ++i)
        s += wb[i] * Cb[(size_t)i * D_ + c0 + col];
    part[ig][col] = s;
    __syncthreads();
    if (t < 64) Bctx[b * D_ + c0 + t] = part[0][t] + part[1][t] + part[2][t] + part[3][t];
}

__global__ __launch_bounds__(192) void k_final(const float* __restrict__ C,
                                               const float* __restrict__ Bctx,
                                               float* __restrict__ out) {
    int row = blockIdx.x;
    int b = row >> 10;
    int t = threadIdx.x;
    float4 c = *(const float4*)(C + (size_t)row * D_ + t * 4);
    float4 g = *(const float4*)(Bctx + (size_t)b * D_ + t * 4);
    *(float4*)(out + (size_t)row * 3072 + 2304 + t * 4) =
        make_float4(c.x * g.x, c.y * g.y, c.z * g.z, c.w * g.w);
}

extern "C" void kernel_launch(void* const* d_in, const int* in_sizes, int n_in,
                              void* d_out, int out_size, void* d_ws, size_t ws_size,
                              hipStream_t stream) {
    const float* C      = (const float*)d_in[0];
    const float* Q      = (const float*)d_in[1];
    const int*   c_mask = (const int*)d_in[2];
    const int*   q_mask = (const int*)d_in[3];
    const float* w1     = (const float*)d_in[4];
    const float* w2     = (const float*)d_in[5];
    const float* w3     = (const float*)d_in[6];
    float* out = (float*)d_out;
    float* ws  = (float*)d_ws;

    float* qlog   = ws;
    float* rowmax = ws + 2048;
    float* wq2c   = ws + 18432;
    float* Bctx   = ws + 34816;

    k_qlogit<<<512, 256, 0, stream>>>(Q, w2, qlog);
    k_main<<<512, 256, 0, stream>>>(C, Q, c_mask, q_mask, w1, w3, qlog, rowmax, out);
    k_q2c<<<16, 256, 0, stream>>>(rowmax, c_mask, wq2c);
    k_bctx<<<192, 256, 0, stream>>>(C, wq2c, Bctx);
    k_final<<<16384, 192, 0, stream>>>(C, Bctx, out);
}

// Round 3
// 117.999 us; speedup vs baseline: 2.2334x; 1.1174x over previous
//
#include <hip/hip_runtime.h>
#include <math.h>
#include <stdint.h>

#define NEGV -1e9f
typedef float f32x4 __attribute__((ext_vector_type(4)));
typedef short bf16x8 __attribute__((ext_vector_type(8)));
typedef unsigned int u32x4 __attribute__((ext_vector_type(4)));

constexpr int B_ = 16, N_ = 1024, M_ = 128, D_ = 768;
constexpr int NCH = 12;  // 768/64 chunks

// ws layout (bytes):
//   qlog   f32[2048]   @ 0
//   rowmax f32[16384]  @ 8192
//   wq2c   f32[16384]  @ 73728
//   Bctx   f32[12288]  @ 139264
//   QH  bf16 image     @ 196608    (+3145728 each)
//   QL                 @ 3342336
//   QtH                @ 6488064
//   QtL                @ 9633792   (end 12779520)
constexpr size_t OFF_QH = 196608, SZ_Q = 3145728;
constexpr size_t WS_NEED = OFF_QH + 4 * SZ_Q;

__device__ __forceinline__ unsigned short bf_rne(float x) {
    unsigned u = __float_as_uint(x);
    return (unsigned short)((u + 0x7fffu + ((u >> 16) & 1u)) >> 16);
}
__device__ __forceinline__ void splitf(float x, unsigned short& h, unsigned short& l) {
    unsigned short hb = bf_rne(x);
    float hf = __uint_as_float((unsigned)hb << 16);
    h = hb;
    l = bf_rne(x - hf);
}
__device__ __forceinline__ void gl_lds16(const void* g, void* l) {
    __builtin_amdgcn_global_load_lds(
        (const __attribute__((address_space(1))) void*)g,
        (__attribute__((address_space(3))) void*)l, 16, 0, 0);
}

__global__ __launch_bounds__(256) void k_qlogit(const float* __restrict__ Q,
                                                const float* __restrict__ w2,
                                                float* __restrict__ qlog) {
    int idx  = blockIdx.x * 4 + (threadIdx.x >> 6);
    int lane = threadIdx.x & 63;
    const float* q = Q + (size_t)idx * D_;
    float s = 0.f;
    for (int k = lane; k < D_; k += 64) s += q[k] * w2[k];
#pragma unroll
    for (int off = 32; off; off >>= 1) s += __shfl_xor(s, off);
    if (lane == 0) qlog[idx] = s;
}

// One-shot Q conversion: writes pre-swizzled LDS images.
// QH/QL  : per (b,chunk): [j=128][g=8 swz g^(j&7)][8 bf16]   (16384 B/chunk)
// QtH/QtL: per (b,chunk): [dd=64][gj=16 swz gj^(dd&7)][8 bf16] (16384 B/chunk)
__global__ __launch_bounds__(256) void k_prep(const float* __restrict__ Q,
                                              char* __restrict__ qh, char* __restrict__ ql,
                                              char* __restrict__ qth, char* __restrict__ qtl) {
    int b = blockIdx.x / NCH, c = blockIdx.x % NCH;
    int t = threadIdx.x;
    __shared__ unsigned sT[128][66];
    int j = t >> 1, half = t & 1;
    const float* src = Q + ((size_t)(b * M_ + j)) * D_ + c * 64 + half * 32;
    unsigned short hs[32], ls[32];
#pragma unroll
    for (int u = 0; u < 8; ++u) {
        float4 v = *(const float4*)(src + u * 4);
        float f[4] = {v.x, v.y, v.z, v.w};
#pragma unroll
        for (int e = 0; e < 4; ++e) {
            unsigned short h, l; splitf(f[e], h, l);
            int idx = u * 4 + e;
            hs[idx] = h; ls[idx] = l;
            sT[j][half * 32 + idx] = ((unsigned)h << 16) | (unsigned)l;
        }
    }
    size_t cb = ((size_t)(b * NCH + c)) * 16384;
#pragma unroll
    for (int u2 = 0; u2 < 4; ++u2) {
        int g = half * 4 + u2;
        bf16x8 hv, lv;
#pragma unroll
        for (int e = 0; e < 8; ++e) { hv[e] = (short)hs[u2 * 8 + e]; lv[e] = (short)ls[u2 * 8 + e]; }
        size_t off = cb + (size_t)j * 128 + (size_t)((g ^ (j & 7)) * 16);
        *(bf16x8*)(qh + off) = hv;
        *(bf16x8*)(ql + off) = lv;
    }
    __syncthreads();
#pragma unroll
    for (int u = 0; u < 4; ++u) {
        int id = t * 4 + u;
        int dd = id >> 4, gj = id & 15;
        bf16x8 hv, lv;
#pragma unroll
        for (int e = 0; e < 8; ++e) {
            unsigned p = sT[gj * 8 + e][dd];
            hv[e] = (short)(p >> 16); lv[e] = (short)(p & 0xffffu);
        }
        size_t off = cb + (size_t)dd * 256 + (size_t)((gj ^ (dd & 7)) * 16);
        *(bf16x8*)(qth + off) = hv;
        *(bf16x8*)(qtl + off) = lv;
    }
}

// 512 blocks (XCD-swizzled): b = bid>>5, 32 rows. 4 waves: rg = w>>1, jh = w&1.
__global__ __launch_bounds__(256, 2) void k_main_fast(const float* __restrict__ C,
                                                      const int* __restrict__ c_mask,
                                                      const int* __restrict__ q_mask,
                                                      const float* __restrict__ w1,
                                                      const float* __restrict__ w3,
                                                      const float* __restrict__ qlog,
                                                      const char* __restrict__ qh,
                                                      const char* __restrict__ ql,
                                                      const char* __restrict__ qth,
                                                      const char* __restrict__ qtl,
                                                      float* __restrict__ rowmax,
                                                      float* __restrict__ out) {
    const int bid = (blockIdx.x & 7) * 64 + (blockIdx.x >> 3);  // XCD-chunked, bijective
    const int b  = bid >> 5;
    const int r0 = (bid & 31) * 32;
    const int t  = threadIdx.x;
    const int wv = t >> 6, lane = t & 63;
    const int rg = wv >> 1, jh = wv & 1;
    const int q4 = (t & 63) >> 4, c15 = t & 15;

    const float* Cb = C + ((size_t)(b * N_ + r0)) * D_;

    __shared__ __align__(16) char uni[49152];
    __shared__ float sW1[D_], sW3[D_];
    __shared__ float sQlog[M_];
    __shared__ int   sQmask[M_];
    __shared__ float sClog[32];
    __shared__ float sRedR[64], sRedM[64], sRedS[64];

    char* sCwH = uni;             // phase1: [32 r][8 g][16B] swz g^(r&7)
    char* sCwL = uni + 4096;
    char* sQH  = uni + 8192;      // phase1: chunk image (16 KB)
    char* sQL  = uni + 24576;
    char* sPH  = uni;             // phase2/3: [32 r][16 gj][16B] swz gj^(r&7) (8 KB)
    char* sPL  = uni + 8192;
    char* sQtH = uni + 16384;     // phase3: chunk image (16 KB)
    char* sQtL = uni + 32768;

    for (int k = t; k < D_; k += 256) { sW1[k] = w1[k]; sW3[k] = w3[k]; }
    if (t < M_) { sQlog[t] = qlog[b * M_ + t]; sQmask[t] = q_mask[b * M_ + t]; }

    f32x4 acc[4] = {};
    float clog = 0.f;
    const int cr = t >> 3, ckq = t & 7;  // C staging: row, k-group

    const size_t qcb = (size_t)(b * NCH) * 16384;

    // ---- Phase 1: S = (C*w3) @ Q^T ----
    for (int kidx = 0; kidx < NCH; ++kidx) {
        int kb = kidx * 64;
        __syncthreads();
        {   // stage C*w3 -> hi/lo bf16 + c_logit partial
            const float* p = Cb + (size_t)cr * D_ + kb + ckq * 8;
            float4 a  = *(const float4*)p;
            float4 bb = *(const float4*)(p + 4);
            float cc[8] = {a.x, a.y, a.z, a.w, bb.x, bb.y, bb.z, bb.w};
            bf16x8 hv, lv;
            int kk = kb + ckq * 8;
#pragma unroll
            for (int e = 0; e < 8; ++e) {
                clog += cc[e] * sW1[kk + e];
                unsigned short h, l;
                splitf(cc[e] * sW3[kk + e], h, l);
                hv[e] = (short)h; lv[e] = (short)l;
            }
            int pg = (ckq ^ (cr & 7)) * 16;
            *(bf16x8*)(sCwH + cr * 128 + pg) = hv;
            *(bf16x8*)(sCwL + cr * 128 + pg) = lv;
        }
        {   // stage Q chunk image via async global->LDS
            size_t gb = qcb + (size_t)kidx * 16384;
#pragma unroll
            for (int it = 0; it < 4; ++it) {
                int off = it * 4096 + wv * 1024;
                gl_lds16(qh + gb + off + lane * 16, sQH + off);
                gl_lds16(ql + gb + off + lane * 16, sQL + off);
            }
        }
        __syncthreads();
        const int arow = rg * 16 + c15;
#pragma unroll
        for (int ks = 0; ks < 2; ++ks) {
            int g  = ks * 4 + q4;
            int pg = (g ^ (c15 & 7)) * 16;
            bf16x8 ah = *(const bf16x8*)(sCwH + arow * 128 + pg);
            bf16x8 al = *(const bf16x8*)(sCwL + arow * 128 + pg);
#pragma unroll
            for (int jt = 0; jt < 4; ++jt) {
                int jr = jh * 64 + jt * 16 + c15;
                bf16x8 bh = *(const bf16x8*)(sQH + jr * 128 + pg);
                bf16x8 bl = *(const bf16x8*)(sQL + jr * 128 + pg);
                acc[jt] = __builtin_amdgcn_mfma_f32_16x16x32_bf16(ah, bh, acc[jt], 0, 0, 0);
                acc[jt] = __builtin_amdgcn_mfma_f32_16x16x32_bf16(ah, bl, acc[jt], 0, 0, 0);
                acc[jt] = __builtin_amdgcn_mfma_f32_16x16x32_bf16(al, bh, acc[jt], 0, 0, 0);
            }
        }
    }

    // ---- Phase 2: logits + masked softmax ----
    clog += __shfl_xor(clog, 1); clog += __shfl_xor(clog, 2); clog += __shfl_xor(clog, 4);
    if ((t & 7) == 0) sClog[cr] = clog;
    __syncthreads();

    float qlg[4]; int qmv[4];
#pragma unroll
    for (int jt = 0; jt < 4; ++jt) {
        int j = jh * 64 + jt * 16 + c15;
        qlg[jt] = sQlog[j]; qmv[jt] = sQmask[j];
    }
    int cmv[4]; float clgr[4];
#pragma unroll
    for (int rr = 0; rr < 4; ++rr) {
        int row = rg * 16 + q4 * 4 + rr;
        cmv[rr]  = c_mask[b * N_ + r0 + row];
        clgr[rr] = sClog[row];
    }
    float mv[4][4], rmx[4], mmx[4];
#pragma unroll
    for (int rr = 0; rr < 4; ++rr) { rmx[rr] = -INFINITY; mmx[rr] = -INFINITY; }
#pragma unroll
    for (int jt = 0; jt < 4; ++jt)
#pragma unroll
        for (int rr = 0; rr < 4; ++rr) {
            float val = acc[jt][rr] + clgr[rr] + qlg[jt];
            float m   = (cmv[rr] | qmv[jt]) ? NEGV : val;
            mv[jt][rr] = m;
            rmx[rr] = fmaxf(rmx[rr], val);
            mmx[rr] = fmaxf(mmx[rr], m);
        }
#pragma unroll
    for (int rr = 0; rr < 4; ++rr)
#pragma unroll
        for (int off = 8; off; off >>= 1) {
            rmx[rr] = fmaxf(rmx[rr], __shfl_xor(rmx[rr], off));
            mmx[rr] = fmaxf(mmx[rr], __shfl_xor(mmx[rr], off));
        }
    if (c15 == 0) {
#pragma unroll
        for (int rr = 0; rr < 4; ++rr) {
            int row = rg * 16 + q4 * 4 + rr;
            sRedR[row * 2 + jh] = rmx[rr];
            sRedM[row * 2 + jh] = mmx[rr];
        }
    }
    __syncthreads();
    float Mm[4], sum[4];
#pragma unroll
    for (int rr = 0; rr < 4; ++rr) {
        int row = rg * 16 + q4 * 4 + rr;
        float Mraw = fmaxf(sRedR[row * 2], sRedR[row * 2 + 1]);
        Mm[rr] = fmaxf(sRedM[row * 2], sRedM[row * 2 + 1]);
        if (jh == 0 && c15 == 0) rowmax[b * N_ + r0 + row] = Mraw;
        sum[rr] = 0.f;
    }
    float p[4][4];
#pragma unroll
    for (int jt = 0; jt < 4; ++jt)
#pragma unroll
        for (int rr = 0; rr < 4; ++rr) {
            float e = __expf(mv[jt][rr] - Mm[rr]);
            p[jt][rr] = e; sum[rr] += e;
        }
#pragma unroll
    for (int rr = 0; rr < 4; ++rr) {
#pragma unroll
        for (int off = 8; off; off >>= 1) sum[rr] += __shfl_xor(sum[rr], off);
        if (c15 == 0) sRedS[(rg * 16 + q4 * 4 + rr) * 2 + jh] = sum[rr];
    }
    __syncthreads();
#pragma unroll
    for (int rr = 0; rr < 4; ++rr) {
        int row = rg * 16 + q4 * 4 + rr;
        float inv = 1.f / (sRedS[row * 2] + sRedS[row * 2 + 1]);
#pragma unroll
        for (int jt = 0; jt < 4; ++jt) {
            float P = p[jt][rr] * inv;
            unsigned short h, l; splitf(P, h, l);
            int j = jh * 64 + jt * 16 + c15;
            int addr = row * 256 + (((j >> 3) ^ (row & 7)) * 16) + (j & 7) * 2;
            *(short*)(sPH + addr) = (short)h;
            *(short*)(sPL + addr) = (short)l;
        }
    }

    // ---- Phase 3: A = P @ Q + fused epilogue ----
    for (int dc = 0; dc < NCH; ++dc) {
        __syncthreads();
        {   // stage Qt chunk image
            size_t gb = qcb + (size_t)dc * 16384;
#pragma unroll
            for (int it = 0; it < 4; ++it) {
                int off = it * 4096 + wv * 1024;
                gl_lds16(qth + gb + off + lane * 16, sQtH + off);
                gl_lds16(qtl + gb + off + lane * 16, sQtL + off);
            }
        }
        __syncthreads();
        f32x4 acc2[2] = {};
        const int prow = rg * 16 + c15;
#pragma unroll
        for (int ks2 = 0; ks2 < 4; ++ks2) {
            int gja = ks2 * 4 + q4;
            int pgp = (gja ^ (prow & 7)) * 16;
            bf16x8 ah = *(const bf16x8*)(sPH + prow * 256 + pgp);
            bf16x8 al = *(const bf16x8*)(sPL + prow * 256 + pgp);
#pragma unroll
            for (int dt = 0; dt < 2; ++dt) {
                int dr  = jh * 32 + dt * 16 + c15;
                int pgq = (gja ^ (dr & 7)) * 16;
                bf16x8 bh = *(const bf16x8*)(sQtH + dr * 256 + pgq);
                bf16x8 bl = *(const bf16x8*)(sQtL + dr * 256 + pgq);
                acc2[dt] = __builtin_amdgcn_mfma_f32_16x16x32_bf16(ah, bh, acc2[dt], 0, 0, 0);
                acc2[dt] = __builtin_amdgcn_mfma_f32_16x16x32_bf16(ah, bl, acc2[dt], 0, 0, 0);
                acc2[dt] = __builtin_amdgcn_mfma_f32_16x16x32_bf16(al, bh, acc2[dt], 0, 0, 0);
            }
        }
#pragma unroll
        for (int dt = 0; dt < 2; ++dt)
#pragma unroll
            for (int rr = 0; rr < 4; ++rr) {
                int row  = rg * 16 + q4 * 4 + rr;
                int dcol = dc * 64 + jh * 32 + dt * 16 + c15;
                float a = acc2[dt][rr];
                float c = Cb[(size_t)row * D_ + dcol];
                size_t ob = (size_t)(b * N_ + r0 + row) * 3072;
                out[ob + dcol] = c;
                out[ob + 768 + dcol] = a;
                out[ob + 1536 + dcol] = c * a;
            }
    }
}

// ---------------- fallback (R2-proven) ----------------
__global__ __launch_bounds__(256, 2) void k_main_fb(const float* __restrict__ C,
                                                    const float* __restrict__ Q,
                                                    const int* __restrict__ c_mask,
                                                    const int* __restrict__ q_mask,
                                                    const float* __restrict__ w1,
                                                    const float* __restrict__ w3,
                                                    const float* __restrict__ qlog,
                                                    float* __restrict__ rowmax,
                                                    float* __restrict__ out) {
    const int bid = (blockIdx.x & 7) * 64 + (blockIdx.x >> 3);
    const int b  = bid >> 5;
    const int r0 = (bid & 31) * 32;
    const int t  = threadIdx.x;
    const int wv = t >> 6;
    const int rg = wv >> 1, jh = wv & 1;
    const int q4 = (t & 63) >> 4, c15 = t & 15;

    const float* Cb = C + ((size_t)(b * N_ + r0)) * D_;
    const float* Qb = Q + (size_t)b * M_ * D_;

    __shared__ __align__(16) char uni[49152];
    __shared__ float sW1[D_], sW3[D_];
    __shared__ float sQlog[M_];
    __shared__ int   sQmask[M_];
    __shared__ float sClog[32];
    __shared__ float sRedR[64], sRedM[64], sRedS[64];

    char* sCwH = uni;
    char* sCwL = uni + 4096;
    char* sQH  = uni + 8192;
    char* sQL  = uni + 24576;
    char* sPt  = uni;
    char* sQtP = uni + 16384;

    for (int k = t; k < D_; k += 256) { sW1[k] = w1[k]; sW3[k] = w3[k]; }
    if (t < M_) { sQlog[t] = qlog[b * M_ + t]; sQmask[t] = q_mask[b * M_ + t]; }

    f32x4 acc[4] = {};
    float clog = 0.f;
    const int cr = t >> 3, ckq = t & 7;
    const int qj = t >> 1, qk0 = (t & 1) * 32;

    for (int kb = 0; kb < D_; kb += 64) {
        __syncthreads();
        {
            const float* p = Cb + (size_t)cr * D_ + kb + ckq * 8;
            float4 a  = *(const float4*)p;
            float4 bb = *(const float4*)(p + 4);
            float cc[8] = {a.x, a.y, a.z, a.w, bb.x, bb.y, bb.z, bb.w};
            bf16x8 hv, lv;
            int kk = kb + ckq * 8;
#pragma unroll
            for (int e = 0; e < 8; ++e) {
                clog += cc[e] * sW1[kk + e];
                unsigned short h, l;
                splitf(cc[e] * sW3[kk + e], h, l);
                hv[e] = (short)h; lv[e] = (short)l;
            }
            int pg = (ckq ^ (cr & 7)) * 16;
            *(bf16x8*)(sCwH + cr * 128 + pg) = hv;
            *(bf16x8*)(sCwL + cr * 128 + pg) = lv;
        }
        {
            const float* p = Qb + (size_t)qj * D_ + kb + qk0;
#pragma unroll
            for (int u = 0; u < 4; ++u) {
                float4 a  = *(const float4*)(p + u * 8);
                float4 bb = *(const float4*)(p + u * 8 + 4);
                float qq[8] = {a.x, a.y, a.z, a.w, bb.x, bb.y, bb.z, bb.w};
                bf16x8 hv, lv;
#pragma unroll
                for (int e = 0; e < 8; ++e) {
                    unsigned short h, l;
                    splitf(qq[e], h, l);
                    hv[e] = (short)h; lv[e] = (short)l;
                }
                int g  = (t & 1) * 4 + u;
                int pg = (g ^ (qj & 7)) * 16;
                *(bf16x8*)(sQH + qj * 128 + pg) = hv;
                *(bf16x8*)(sQL + qj * 128 + pg) = lv;
            }
        }
        __syncthreads();
        const int arow = rg * 16 + c15;
#pragma unroll
        for (int ks = 0; ks < 2; ++ks) {
            int g  = ks * 4 + q4;
            int pg = (g ^ (c15 & 7)) * 16;
            bf16x8 ah = *(const bf16x8*)(sCwH + arow * 128 + pg);
            bf16x8 al = *(const bf16x8*)(sCwL + arow * 128 + pg);
#pragma unroll
            for (int jt = 0; jt < 4; ++jt) {
                int jr = jh * 64 + jt * 16 + c15;
                bf16x8 bh = *(const bf16x8*)(sQH + jr * 128 + pg);
                bf16x8 bl = *(const bf16x8*)(sQL + jr * 128 + pg);
                acc[jt] = __builtin_amdgcn_mfma_f32_16x16x32_bf16(ah, bh, acc[jt], 0, 0, 0);
                acc[jt] = __builtin_amdgcn_mfma_f32_16x16x32_bf16(ah, bl, acc[jt], 0, 0, 0);
                acc[jt] = __builtin_amdgcn_mfma_f32_16x16x32_bf16(al, bh, acc[jt], 0, 0, 0);
            }
        }
    }

    clog += __shfl_xor(clog, 1); clog += __shfl_xor(clog, 2); clog += __shfl_xor(clog, 4);
    if ((t & 7) == 0) sClog[cr] = clog;
    __syncthreads();

    float qlg[4]; int qmv[4];
#pragma unroll
    for (int jt = 0; jt < 4; ++jt) {
        int j = jh * 64 + jt * 16 + c15;
        qlg[jt] = sQlog[j]; qmv[jt] = sQmask[j];
    }
    int cmv[4]; float clgr[4];
#pragma unroll
    for (int rr = 0; rr < 4; ++rr) {
        int row = rg * 16 + q4 * 4 + rr;
        cmv[rr]  = c_mask[b * N_ + r0 + row];
        clgr[rr] = sClog[row];
    }
    float mv[4][4], rmx[4], mmx[4];
#pragma unroll
    for (int rr = 0; rr < 4; ++rr) { rmx[rr] = -INFINITY; mmx[rr] = -INFINITY; }
#pragma unroll
    for (int jt = 0; jt < 4; ++jt)
#pragma unroll
        for (int rr = 0; rr < 4; ++rr) {
            float val = acc[jt][rr] + clgr[rr] + qlg[jt];
            float m   = (cmv[rr] | qmv[jt]) ? NEGV : val;
            mv[jt][rr] = m;
            rmx[rr] = fmaxf(rmx[rr], val);
            mmx[rr] = fmaxf(mmx[rr], m);
        }
#pragma unroll
    for (int rr = 0; rr < 4; ++rr)
#pragma unroll
        for (int off = 8; off; off >>= 1) {
            rmx[rr] = fmaxf(rmx[rr], __shfl_xor(rmx[rr], off));
            mmx[rr] = fmaxf(mmx[rr], __shfl_xor(mmx[rr], off));
        }
    if (c15 == 0) {
#pragma unroll
        for (int rr = 0; rr < 4; ++rr) {
            int row = rg * 16 + q4 * 4 + rr;
            sRedR[row * 2 + jh] = rmx[rr];
            sRedM[row * 2 + jh] = mmx[rr];
        }
    }
    __syncthreads();
    float Mm[4], sum[4];
#pragma unroll
    for (int rr = 0; rr < 4; ++rr) {
        int row = rg * 16 + q4 * 4 + rr;
        float Mraw = fmaxf(sRedR[row * 2], sRedR[row * 2 + 1]);
        Mm[rr] = fmaxf(sRedM[row * 2], sRedM[row * 2 + 1]);
        if (jh == 0 && c15 == 0) rowmax[b * N_ + r0 + row] = Mraw;
        sum[rr] = 0.f;
    }
    float p[4][4];
#pragma unroll
    for (int jt = 0; jt < 4; ++jt)
#pragma unroll
        for (int rr = 0; rr < 4; ++rr) {
            float e = __expf(mv[jt][rr] - Mm[rr]);
            p[jt][rr] = e; sum[rr] += e;
        }
#pragma unroll
    for (int rr = 0; rr < 4; ++rr) {
#pragma unroll
        for (int off = 8; off; off >>= 1) sum[rr] += __shfl_xor(sum[rr], off);
        if (c15 == 0) sRedS[(rg * 16 + q4 * 4 + rr) * 2 + jh] = sum[rr];
    }
    __syncthreads();
#pragma unroll
    for (int rr = 0; rr < 4; ++rr) {
        int row = rg * 16 + q4 * 4 + rr;
        float inv = 1.f / (sRedS[row * 2] + sRedS[row * 2 + 1]);
#pragma unroll
        for (int jt = 0; jt < 4; ++jt) {
            float P = p[jt][rr] * inv;
            unsigned short h, l; splitf(P, h, l);
            unsigned pk = ((unsigned)h << 16) | (unsigned)l;
            int j  = jh * 64 + jt * 16 + c15;
            int gu = j >> 2;
            *(unsigned*)(sPt + row * 512 + ((gu ^ (row & 7)) * 16) + (j & 3) * 4) = pk;
        }
    }

    const int pj = t >> 1, pdh = (t & 1) * 32;
    for (int d0 = 0; d0 < D_; d0 += 64) {
        __syncthreads();
        {
            const float* p = Qb + (size_t)pj * D_ + d0 + pdh;
            int gu = pj >> 2, joff = (pj & 3) * 4;
#pragma unroll
            for (int u = 0; u < 8; ++u) {
                float4 a = *(const float4*)(p + u * 4);
                float qq[4] = {a.x, a.y, a.z, a.w};
#pragma unroll
                for (int e = 0; e < 4; ++e) {
                    unsigned short h, l; splitf(qq[e], h, l);
                    int d = pdh + u * 4 + e;
                    *(unsigned*)(sQtP + d * 512 + ((gu ^ (d & 7)) * 16) + joff) =
                        ((unsigned)h << 16) | (unsigned)l;
                }
            }
        }
        __syncthreads();
        f32x4 acc2[2] = {};
        const int prow = rg * 16 + c15;
#pragma unroll
        for (int ks2 = 0; ks2 < 4; ++ks2) {
            int gu0 = ks2 * 8 + q4 * 2;
            u32x4 pa = *(const u32x4*)(sPt + prow * 512 + ((gu0 ^ (c15 & 7)) * 16));
            u32x4 pb = *(const u32x4*)(sPt + prow * 512 + (((gu0 + 1) ^ (c15 & 7)) * 16));
            bf16x8 phi, plo;
#pragma unroll
            for (int e = 0; e < 4; ++e) {
                phi[e]     = (short)(pa[e] >> 16); plo[e]     = (short)(pa[e] & 0xffffu);
                phi[e + 4] = (short)(pb[e] >> 16); plo[e + 4] = (short)(pb[e] & 0xffffu);
            }
#pragma unroll
            for (int dt = 0; dt < 2; ++dt) {
                int dr = jh * 32 + dt * 16 + c15;
                u32x4 qa = *(const u32x4*)(sQtP + dr * 512 + ((gu0 ^ (dr & 7)) * 16));
                u32x4 qb = *(const u32x4*)(sQtP + dr * 512 + (((gu0 + 1) ^ (dr & 7)) * 16));
                bf16x8 bh, bl;
#pragma unroll
                for (int e = 0; e < 4; ++e) {
                    bh[e]     = (short)(qa[e] >> 16); bl[e]     = (short)(qa[e] & 0xffffu);
                    bh[e + 4] = (short)(qb[e] >> 16); bl[e + 4] = (short)(qb[e] & 0xffffu);
                }
                acc2[dt] = __builtin_amdgcn_mfma_f32_16x16x32_bf16(phi, bh, acc2[dt], 0, 0, 0);
                acc2[dt] = __builtin_amdgcn_mfma_f32_16x16x32_bf16(phi, bl, acc2[dt], 0, 0, 0);
                acc2[dt] = __builtin_amdgcn_mfma_f32_16x16x32_bf16(plo, bh, acc2[dt], 0, 0, 0);
            }
        }
#pragma unroll
        for (int dt = 0; dt < 2; ++dt)
#pragma unroll
            for (int rr = 0; rr < 4; ++rr) {
                int row  = rg * 16 + q4 * 4 + rr;
                int dcol = d0 + jh * 32 + dt * 16 + c15;
                float a = acc2[dt][rr];
                float c = Cb[(size_t)row * D_ + dcol];
                size_t ob = (size_t)(b * N_ + r0 + row) * 3072;
                out[ob + dcol] = c;
                out[ob + 768 + dcol] = a;
                out[ob + 1536 + dcol] = c * a;
            }
    }
}

__global__ __launch_bounds__(256) void k_q2c(const float* __restrict__ rowmax,
                                             const int* __restrict__ c_mask,
                                             float* __restrict__ wq2c) {
    int b = blockIdx.x, t = threadIdx.x;
    __shared__ float red[8];
    float l[4];
#pragma unroll
    for (int u = 0; u < 4; ++u) {
        int i = t + u * 256;
        l[u] = (c_mask[b * N_ + i] != 0) ? NEGV : rowmax[b * N_ + i];
    }
    float mx = fmaxf(fmaxf(l[0], l[1]), fmaxf(l[2], l[3]));
#pragma unroll
    for (int off = 32; off; off >>= 1) mx = fmaxf(mx, __shfl_xor(mx, off));
    if ((t & 63) == 0) red[t >> 6] = mx;
    __syncthreads();
    mx = fmaxf(fmaxf(red[0], red[1]), fmaxf(red[2], red[3]));
    float e[4], s = 0.f;
#pragma unroll
    for (int u = 0; u < 4; ++u) { e[u] = __expf(l[u] - mx); s += e[u]; }
#pragma unroll
    for (int off = 32; off; off >>= 1) s += __shfl_xor(s, off);
    if ((t & 63) == 0) red[4 + (t >> 6)] = s;
    __syncthreads();
    s = red[4] + red[5] + red[6] + red[7];
    float inv = 1.f / s;
#pragma unroll
    for (int u = 0; u < 4; ++u) wq2c[b * N_ + t + u * 256] = e[u] * inv;
}

__global__ __launch_bounds__(256) void k_bctx(const float* __restrict__ C,
                                              const float* __restrict__ wq2c,
                                              float* __restrict__ Bctx) {
    int b  = blockIdx.x / 12;
    int c0 = (blockIdx.x % 12) * 64;
    int t  = threadIdx.x;
    int col = t & 63, ig = t >> 6;
    __shared__ float part[4][64];
    const float* wb = wq2c + b * N_;
    const float* Cb = C + (size_t)b * N_ * D_;
    float s = 0.f;
    for (int i = ig * 256; i < ig * 256 + 256; ++i)
        s += wb[i] * Cb[(size_t)i * D_ + c0 + col];
    part[ig][col] = s;
    __syncthreads();
    if (t < 64) Bctx[b * D_ + c0 + t] = part[0][t] + part[1][t] + part[2][t] + part[3][t];
}

__global__ __launch_bounds__(192) void k_final(const float* __restrict__ C,
                                               const float* __restrict__ Bctx,
                                               float* __restrict__ out) {
    int row = blockIdx.x;
    int b = row >> 10;
    int t = threadIdx.x;
    float4 c = *(const float4*)(C + (size_t)row * D_ + t * 4);
    float4 g = *(const float4*)(Bctx + (size_t)b * D_ + t * 4);
    *(float4*)(out + (size_t)row * 3072 + 2304 + t * 4) =
        make_float4(c.x * g.x, c.y * g.y, c.z * g.z, c.w * g.w);
}

extern "C" void kernel_launch(void* const* d_in, const int* in_sizes, int n_in,
                              void* d_out, int out_size, void* d_ws, size_t ws_size,
                              hipStream_t stream) {
    const float* C      = (const float*)d_in[0];
    const float* Q      = (const float*)d_in[1];
    const int*   c_mask = (const int*)d_in[2];
    const int*   q_mask = (const int*)d_in[3];
    const float* w1     = (const float*)d_in[4];
    const float* w2     = (const float*)d_in[5];
    const float* w3     = (const float*)d_in[6];
    float* out = (float*)d_out;
    char*  wsb = (char*)d_ws;

    float* qlog   = (float*)(wsb + 0);
    float* rowmax = (float*)(wsb + 8192);
    float* wq2c   = (float*)(wsb + 73728);
    float* Bctx   = (float*)(wsb + 139264);

    k_qlogit<<<512, 256, 0, stream>>>(Q, w2, qlog);
    if (ws_size >= WS_NEED) {
        char* qh  = wsb + OFF_QH;
        char* ql  = qh + SZ_Q;
        char* qth = ql + SZ_Q;
        char* qtl = qth + SZ_Q;
        k_prep<<<B_ * NCH, 256, 0, stream>>>(Q, qh, ql, qth, qtl);
        k_main_fast<<<512, 256, 0, stream>>>(C, c_mask, q_mask, w1, w3, qlog,
                                             qh, ql, qth, qtl, rowmax, out);
    } else {
        k_main_fb<<<512, 256, 0, stream>>>(C, Q, c_mask, q_mask, w1, w3, qlog, rowmax, out);
    }
    k_q2c<<<16, 256, 0, stream>>>(rowmax, c_mask, wq2c);
    k_bctx<<<192, 256, 0, stream>>>(C, wq2c, Bctx);
    k_final<<<16384, 192, 0, stream>>>(C, Bctx, out);
}